// Round 5
// baseline (488.546 us; speedup 1.0000x reference)
//
#include <hip/hip_runtime.h>
#include <cstdint>
#include <cstddef>

#define N_NODES 8192
#define IN_DIM  256
#define OUT_DIM 64
#define HEADS   2
#define FEAT    128           // OUT_DIM*HEADS
#define NTILES  9             // 144 B-cols: 128 feat + 2 denom + 14 pad
#define ACC_STRIDE 132
#define KSPLIT  8
#define PACK_BLOCKS 2048      // bit-pack portion of the fused first kernel

typedef __bf16 bf16x8 __attribute__((ext_vector_type(8)));
typedef float  f32x4  __attribute__((ext_vector_type(4)));
typedef int    i32x4  __attribute__((ext_vector_type(4)));
typedef unsigned uu32x4 __attribute__((ext_vector_type(4)));

static __device__ __forceinline__ unsigned short f2bf(float f) {
  unsigned u = __float_as_uint(f);
  u += 0x7FFFu + ((u >> 16) & 1u);     // round-to-nearest-even
  return (unsigned short)(u >> 16);
}

// ---------------------------------------------------------------- k_prep_pack
// Fused launch of two independent jobs (co-resident on CUs, overlapping
// BW-bound pack with VALU/LDS-bound prep):
//  blocks 0..2047: bit-pack adj (268 MB int32 -> 8.4 MB bitmask, streaming,
//                  contiguous; thread t packs ints [row*8192 + t*32 .. +31]
//                  into bm[row*256+t], little-endian bit order).
//  blocks 2048..2303: H-tile matmul + er reduction + exp + bf16 frag pack
//                  (identical to previous k_prep, kb = blockIdx.x - 2048).
__global__ __launch_bounds__(256) void k_prep_pack(const float* __restrict__ x,
                                                   const float* __restrict__ W,
                                                   const float* __restrict__ attn_r,
                                                   const int* __restrict__ adj,
                                                   uint4* __restrict__ frag,
                                                   unsigned* __restrict__ bm) {
  __shared__ float xs[32][68];               // [row][k] 8.7 KB
  __shared__ float wl[128][68];              // [col][k] 34.8 KB
  __shared__ unsigned short pk[32][146];     // bf16 pack buffer 9.3 KB

  const int tid = threadIdx.x;

  if (blockIdx.x < PACK_BLOCKS) {
    // ---- bit-pack path: 4 rows per block, 1 row per block-pass ----
#pragma unroll
    for (int rr = 0; rr < 4; ++rr) {
      const int row = blockIdx.x * 4 + rr;
      const i32x4* p = (const i32x4*)(adj + (size_t)row * N_NODES) + tid * 8;
      unsigned w = 0;
#pragma unroll
      for (int i = 0; i < 8; ++i) {
        i32x4 v = __builtin_nontemporal_load(p + i);
        w |= (v[0] != 0 ? 1u : 0u) << (i*4 + 0);
        w |= (v[1] != 0 ? 1u : 0u) << (i*4 + 1);
        w |= (v[2] != 0 ? 1u : 0u) << (i*4 + 2);
        w |= (v[3] != 0 ? 1u : 0u) << (i*4 + 3);
      }
      bm[(size_t)row * 256 + tid] = w;
    }
    return;
  }

  // ---- prep path ----
  const int kb = blockIdx.x - PACK_BLOCKS;   // 0..255
  const int tx = tid & 15, ty = tid >> 4;    // ty 0..15
  const int j0 = kb * 32;

  float acc[2][8] = {};                      // rows ty, ty+16; cols tx+jj*16

  for (int kc = 0; kc < IN_DIM; kc += 64) {
    __syncthreads();
#pragma unroll
    for (int p = 0; p < 2; p++) {
      const int slot = p*256 + tid;
      const int r = slot >> 4, k4 = slot & 15;
      *(float4*)&xs[r][k4*4] = *(const float4*)(x + (size_t)(j0 + r)*IN_DIM + kc + k4*4);
    }
#pragma unroll
    for (int p = 0; p < 8; p++) {
      const int slot = p*256 + tid;
      const int r = slot >> 4, k4 = slot & 15;
      *(float4*)&wl[r][k4*4] = *(const float4*)(W + (size_t)r*IN_DIM + kc + k4*4);
    }
    __syncthreads();
#pragma unroll
    for (int k4 = 0; k4 < 16; k4++) {
      float4 xr[2], wr[8];
#pragma unroll
      for (int i = 0; i < 2; i++) xr[i] = *(const float4*)&xs[ty + i*16][k4*4];
#pragma unroll
      for (int jj = 0; jj < 8; jj++) wr[jj] = *(const float4*)&wl[tx + jj*16][k4*4];
#pragma unroll
      for (int i = 0; i < 2; i++)
#pragma unroll
        for (int jj = 0; jj < 8; jj++)
          acc[i][jj] += xr[i].x*wr[jj].x + xr[i].y*wr[jj].y +
                        xr[i].z*wr[jj].z + xr[i].w*wr[jj].w;
    }
  }

  float ar[8];
#pragma unroll
  for (int jj = 0; jj < 8; jj++)
    ar[jj] = attn_r[((jj >> 2)) * OUT_DIM + ((tx + jj*16) & 63)];
  float e0[2] = {}, e1[2] = {};
#pragma unroll
  for (int i = 0; i < 2; i++) {
#pragma unroll
    for (int jj = 0; jj < 4; jj++) e0[i] += acc[i][jj] * ar[jj];
#pragma unroll
    for (int jj = 4; jj < 8; jj++) e1[i] += acc[i][jj] * ar[jj];
  }
#pragma unroll
  for (int m = 1; m <= 8; m <<= 1) {
#pragma unroll
    for (int i = 0; i < 2; i++) {
      e0[i] += __shfl_xor(e0[i], m);
      e1[i] += __shfl_xor(e1[i], m);
    }
  }
  float w0[2], w1[2];
#pragma unroll
  for (int i = 0; i < 2; i++) { w0[i] = __expf(e0[i]); w1[i] = __expf(e1[i]); }

#pragma unroll
  for (int i = 0; i < 2; i++) {
    const int row = ty + i*16;
#pragma unroll
    for (int jj = 0; jj < 8; jj++)
      pk[row][tx + jj*16] = f2bf((jj < 4 ? w0[i] : w1[i]) * acc[i][jj]);
    pk[row][128 + tx] = (tx == 0) ? f2bf(w0[i]) : (tx == 1) ? f2bf(w1[i]) : 0;
  }
  __syncthreads();

#pragma unroll
  for (int t = 0; t < 3; t++) {
    const int wid = t*256 + tid;
    if (wid < 576) {
      const int l = wid & 63, n = wid >> 6;
      const int col = n*16 + (l & 15), jb = (l >> 4) * 8;
      uint4 o;
      o.x = (unsigned)pk[jb+0][col] | ((unsigned)pk[jb+1][col] << 16);
      o.y = (unsigned)pk[jb+2][col] | ((unsigned)pk[jb+3][col] << 16);
      o.z = (unsigned)pk[jb+4][col] | ((unsigned)pk[jb+5][col] << 16);
      o.w = (unsigned)pk[jb+6][col] | ((unsigned)pk[jb+7][col] << 16);
      frag[((size_t)kb*NTILES + n)*64 + l] = o;
    }
  }
}

// ---------------------------------------------------------------- k_main
// accum[ks][8192][132] = adj[:, ks-slice] @ B[ks-slice, 144]  (bf16 MFMA, fp32 acc)
// Bitmask A: per kk-step a lane's whole A-fragment is ONE byte of bm
// (bits = adj[row][k=kk*32+quad*8 .. +7]) -> no LDS, no barriers, ~16 KB of
// A-traffic per block (L2/L3-resident after pack). A bit-words prefetched one
// 4-step group ahead in named i32x4 regs (all static indexing — no scratch).
// B frags register-double-buffered from L2 (2.36 MB, fully resident).
// Wave = 32 rows (2 MFMA strips): 9 B-loads feed 18 MFMAs per kk.
// Grid 512 = 64 mb x 8 ks; 4 waves/block; ~190 VGPR -> 2 blocks/CU.
__global__ __launch_bounds__(256, 2) void k_main(const unsigned* __restrict__ bm,
                                                 const uint4* __restrict__ fragB,
                                                 float* __restrict__ accum) {
  const int mb = blockIdx.x >> 3;         // 0..63
  const int ks = blockIdx.x & 7;          // 0..7
  const int tid = threadIdx.x;
  const int wave = tid >> 6, lane = tid & 63;
  const int m16 = lane & 15, quad = lane >> 4;

  const int row0 = mb*128 + wave*32 + m16;              // strip0 row
  const i32x4* a0p = (const i32x4*)bm + (size_t)row0*64 + ks*8;  // 4 u32 = 4 kk-steps
  const i32x4* a1p = a0p + (size_t)16*64;               // strip1 (row0+16)
  const uu32x4* bb = (const uu32x4*)fragB + (size_t)(ks*32)*NTILES*64 + lane;

  f32x4 acc0[NTILES], acc1[NTILES];
#pragma unroll
  for (int n = 0; n < NTILES; n++) {
    acc0[n] = (f32x4){0.f, 0.f, 0.f, 0.f};
    acc1[n] = (f32x4){0.f, 0.f, 0.f, 0.f};
  }

  uu32x4 bvA[NTILES], bvB[NTILES];

  auto unpack = [&](unsigned wbits) -> bf16x8 {
    const unsigned b = (wbits >> (quad * 8)) & 0xFFu;
    unsigned u0 = (b & 1u   ? 0x3F80u : 0u) | (b & 2u   ? 0x3F800000u : 0u);
    unsigned u1 = (b & 4u   ? 0x3F80u : 0u) | (b & 8u   ? 0x3F800000u : 0u);
    unsigned u2 = (b & 16u  ? 0x3F80u : 0u) | (b & 32u  ? 0x3F800000u : 0u);
    unsigned u3 = (b & 64u  ? 0x3F80u : 0u) | (b & 128u ? 0x3F800000u : 0u);
    uu32x4 u = {u0, u1, u2, u3};
    return __builtin_bit_cast(bf16x8, u);
  };

  // prologue: A group 0, B(0)
  i32x4 aC0 = a0p[0], aC1 = a1p[0];
#pragma unroll
  for (int t = 0; t < NTILES; t++) bvA[t] = bb[(size_t)t*64];

  for (int g = 0; g < 8; ++g) {             // 8 groups x 4 kk-steps
    // prefetch next A bit-group (g=7 reads 16B past slice — safe inside ws)
    i32x4 aN0 = a0p[g + 1];
    i32x4 aN1 = a1p[g + 1];
#pragma unroll
    for (int j = 0; j < 4; ++j) {
      const int kk = g*4 + j;
      // load B(kk+1) into the buffer not in use (kk=31 reads 9KB past fragB — safe inside ws)
      const uu32x4* bp = bb + (size_t)(kk + 1)*NTILES*64;
      if ((j & 1) == 0) {
#pragma unroll
        for (int t = 0; t < NTILES; t++) bvB[t] = bp[(size_t)t*64];
      } else {
#pragma unroll
        for (int t = 0; t < NTILES; t++) bvA[t] = bp[(size_t)t*64];
      }
      bf16x8 af0 = unpack((unsigned)aC0[j]);
      bf16x8 af1 = unpack((unsigned)aC1[j]);
      const uu32x4* bv = ((j & 1) == 0) ? bvA : bvB;   // static after unroll
#pragma unroll
      for (int n = 0; n < NTILES; n++) {
        bf16x8 bfr = __builtin_bit_cast(bf16x8, bv[n]);
        acc0[n] = __builtin_amdgcn_mfma_f32_16x16x32_bf16(af0, bfr, acc0[n], 0, 0, 0);
      }
#pragma unroll
      for (int n = 0; n < NTILES; n++) {
        bf16x8 bfr = __builtin_bit_cast(bf16x8, bv[n]);
        acc1[n] = __builtin_amdgcn_mfma_f32_16x16x32_bf16(af1, bfr, acc1[n], 0, 0, 0);
      }
    }
    aC0 = aN0; aC1 = aN1;
  }

  // epilogue: C/D layout col=lane&15, row=quad*4+reg. Plain stores.
  const int rb0 = mb*128 + wave*32 + quad*4;
  float* op = accum + (size_t)ks*N_NODES*ACC_STRIDE;
#pragma unroll
  for (int n = 0; n < NTILES; n++) {
    if (n == 8 && m16 >= HEADS) continue;  // cols 130..143 are padding
#pragma unroll
    for (int r = 0; r < 4; r++) {
      op[(size_t)(rb0 + r)*ACC_STRIDE + n*16 + m16]      = acc0[n][r];
      op[(size_t)(rb0 + 16 + r)*ACC_STRIDE + n*16 + m16] = acc1[n][r];
    }
  }
}

// ---------------------------------------------------------------- k_div
// out[i][c] = (sum_ks num) / (sum_ks den); vectorized f32x4, 8 rows/block.
__global__ void k_div(const float* __restrict__ acc, float* __restrict__ out) {
  const int tid = threadIdx.x;
  const int r = tid >> 5, c4 = (tid & 31) << 2;   // 8 rows x 32 lanes x float4
  const int i = blockIdx.x * 8 + r;
  const int h = c4 >> 6;
  f32x4 num = (f32x4){0.f, 0.f, 0.f, 0.f};
  float den = 0.f;
#pragma unroll
  for (int s = 0; s < KSPLIT; s++) {
    const float* p = acc + ((size_t)s*N_NODES + i)*ACC_STRIDE;
    num += *(const f32x4*)(p + c4);
    den += p[FEAT + h];
  }
  f32x4 o = num / (f32x4){den, den, den, den};
  *(f32x4*)(out + (size_t)i*FEAT + c4) = o;
}

// ---------------------------------------------------------------- launch
extern "C" void kernel_launch(void* const* d_in, const int* in_sizes, int n_in,
                              void* d_out, int out_size, void* d_ws, size_t ws_size,
                              hipStream_t stream) {
  const float* x      = (const float*)d_in[0];
  const int*   adj    = (const int*)  d_in[1];
  const float* W      = (const float*)d_in[2];
  // d_in[3] = attn_l: cancels in softmax over j — unused.
  const float* attn_r = (const float*)d_in[4];

  char* ws = (char*)d_ws;
  uint4*    frag = (uint4*)(ws + 0);           // 2.36 MB
  unsigned* bm   = (unsigned*)(ws + (4u << 20));   // 8.39 MB bitmask @ 4 MB
  float*    acc  = (float*)(ws + (16u << 20));     // 8 x 4.33 MB @ 16 MB
  float*    out  = (float*)d_out;

  hipLaunchKernelGGL(k_prep_pack, dim3(PACK_BLOCKS + 256), dim3(256), 0, stream,
                     x, W, attn_r, adj, frag, bm);
  hipLaunchKernelGGL(k_main, dim3(512),  dim3(256), 0, stream, bm, frag, acc);
  hipLaunchKernelGGL(k_div,  dim3(1024), dim3(256), 0, stream, acc, out);
}

// Round 6
// 413.354 us; speedup vs baseline: 1.1819x; 1.1819x over previous
//
#include <hip/hip_runtime.h>
#include <cstdint>
#include <cstddef>

#define N_NODES 8192
#define IN_DIM  256
#define OUT_DIM 64
#define HEADS   2
#define FEAT    128           // OUT_DIM*HEADS
#define NTILES  9             // 144 B-cols: 128 feat + 2 denom + 14 pad
#define ACC_STRIDE 132
#define KSPLIT  8

typedef __bf16 bf16x8 __attribute__((ext_vector_type(8)));
typedef float  f32x4  __attribute__((ext_vector_type(4)));
typedef int    i32x4  __attribute__((ext_vector_type(4)));
typedef unsigned uu32x4 __attribute__((ext_vector_type(4)));

static __device__ __forceinline__ unsigned short f2bf(float f) {
  unsigned u = __float_as_uint(f);
  u += 0x7FFFu + ((u >> 16) & 1u);     // round-to-nearest-even
  return (unsigned short)(u >> 16);
}

// ---------------------------------------------------------------- k_pack
// Standalone streaming bit-pack: 268 MB adj -> 8 MB bitmask. Fully coalesced:
// wave reads 1 KB contiguous per instruction (lane l -> bytes l*16), 8 chunks
// (8 KB) in flight per wave. Ballot transpose: chunk c (cols c*256..+255)
// produces 4 u64 masks m_j, bit w of m_j = adj[row][c*256 + w*4 + j].
// Layout: bm64[row*128 + c*4 + j]. Low VGPR, no LDS -> high occupancy.
// Grid 2048 x 256: wave (4/block) packs one row (32 chunks).
__global__ __launch_bounds__(256) void k_pack(const int* __restrict__ adj,
                                              unsigned long long* __restrict__ bm64) {
  const int tid = threadIdx.x;
  const int wv = tid >> 6, lane = tid & 63;
  const int row = blockIdx.x * 4 + wv;
  const i32x4* rp = (const i32x4*)(adj + (size_t)row * N_NODES) + lane;
  unsigned long long* op = bm64 + (size_t)row * 128;

  for (int c = 0; c < 32; c += 8) {
    i32x4 v[8];
#pragma unroll
    for (int i = 0; i < 8; ++i)
      v[i] = __builtin_nontemporal_load(rp + (size_t)(c + i) * 64);
#pragma unroll
    for (int i = 0; i < 8; ++i) {
      unsigned long long m0 = __ballot(v[i][0] != 0);
      unsigned long long m1 = __ballot(v[i][1] != 0);
      unsigned long long m2 = __ballot(v[i][2] != 0);
      unsigned long long m3 = __ballot(v[i][3] != 0);
      unsigned long long mv = (lane == 0) ? m0 : (lane == 1) ? m1
                            : (lane == 2) ? m2 : m3;
      if (lane < 4) op[(c + i) * 4 + lane] = mv;
    }
  }
}

// ---------------------------------------------------------------- k_prep
// Fused: H-tile matmul (registers) + er reduction + exp + bf16 fragment pack.
// 256 blocks; block kb owns source rows j0 = kb*32 .. j0+31, all 128 cols.
__global__ __launch_bounds__(256) void k_prep(const float* __restrict__ x,
                                              const float* __restrict__ W,
                                              const float* __restrict__ attn_r,
                                              uint4* __restrict__ frag) {
  const int kb = blockIdx.x;                 // 0..255
  const int tid = threadIdx.x;
  const int tx = tid & 15, ty = tid >> 4;    // ty 0..15
  const int j0 = kb * 32;

  __shared__ float xs[32][68];               // [row][k] 8.7 KB
  __shared__ float wl[128][68];              // [col][k] 34.8 KB
  __shared__ unsigned short pk[32][146];     // bf16 pack buffer 9.3 KB

  float acc[2][8] = {};                      // rows ty, ty+16; cols tx+jj*16

  for (int kc = 0; kc < IN_DIM; kc += 64) {
    __syncthreads();
#pragma unroll
    for (int p = 0; p < 2; p++) {
      const int slot = p*256 + tid;
      const int r = slot >> 4, k4 = slot & 15;
      *(float4*)&xs[r][k4*4] = *(const float4*)(x + (size_t)(j0 + r)*IN_DIM + kc + k4*4);
    }
#pragma unroll
    for (int p = 0; p < 8; p++) {
      const int slot = p*256 + tid;
      const int r = slot >> 4, k4 = slot & 15;
      *(float4*)&wl[r][k4*4] = *(const float4*)(W + (size_t)r*IN_DIM + kc + k4*4);
    }
    __syncthreads();
#pragma unroll
    for (int k4 = 0; k4 < 16; k4++) {
      float4 xr[2], wr[8];
#pragma unroll
      for (int i = 0; i < 2; i++) xr[i] = *(const float4*)&xs[ty + i*16][k4*4];
#pragma unroll
      for (int jj = 0; jj < 8; jj++) wr[jj] = *(const float4*)&wl[tx + jj*16][k4*4];
#pragma unroll
      for (int i = 0; i < 2; i++)
#pragma unroll
        for (int jj = 0; jj < 8; jj++)
          acc[i][jj] += xr[i].x*wr[jj].x + xr[i].y*wr[jj].y +
                        xr[i].z*wr[jj].z + xr[i].w*wr[jj].w;
    }
  }

  float ar[8];
#pragma unroll
  for (int jj = 0; jj < 8; jj++)
    ar[jj] = attn_r[((jj >> 2)) * OUT_DIM + ((tx + jj*16) & 63)];
  float e0[2] = {}, e1[2] = {};
#pragma unroll
  for (int i = 0; i < 2; i++) {
#pragma unroll
    for (int jj = 0; jj < 4; jj++) e0[i] += acc[i][jj] * ar[jj];
#pragma unroll
    for (int jj = 4; jj < 8; jj++) e1[i] += acc[i][jj] * ar[jj];
  }
#pragma unroll
  for (int m = 1; m <= 8; m <<= 1) {
#pragma unroll
    for (int i = 0; i < 2; i++) {
      e0[i] += __shfl_xor(e0[i], m);
      e1[i] += __shfl_xor(e1[i], m);
    }
  }
  float w0[2], w1[2];
#pragma unroll
  for (int i = 0; i < 2; i++) { w0[i] = __expf(e0[i]); w1[i] = __expf(e1[i]); }

#pragma unroll
  for (int i = 0; i < 2; i++) {
    const int row = ty + i*16;
#pragma unroll
    for (int jj = 0; jj < 8; jj++)
      pk[row][tx + jj*16] = f2bf((jj < 4 ? w0[i] : w1[i]) * acc[i][jj]);
    pk[row][128 + tx] = (tx == 0) ? f2bf(w0[i]) : (tx == 1) ? f2bf(w1[i]) : 0;
  }
  __syncthreads();

#pragma unroll
  for (int t = 0; t < 3; t++) {
    const int wid = t*256 + tid;
    if (wid < 576) {
      const int l = wid & 63, n = wid >> 6;
      const int col = n*16 + (l & 15), jb = (l >> 4) * 8;
      uint4 o;
      o.x = (unsigned)pk[jb+0][col] | ((unsigned)pk[jb+1][col] << 16);
      o.y = (unsigned)pk[jb+2][col] | ((unsigned)pk[jb+3][col] << 16);
      o.z = (unsigned)pk[jb+4][col] | ((unsigned)pk[jb+5][col] << 16);
      o.w = (unsigned)pk[jb+6][col] | ((unsigned)pk[jb+7][col] << 16);
      frag[((size_t)kb*NTILES + n)*64 + l] = o;
    }
  }
}

// ---------------------------------------------------------------- k_main
// accum[ks][8192][132] = adj[:, ks-slice] @ B[ks-slice, 144]  (bf16 MFMA, fp32 acc)
// Bitmask A (ballot layout): chunk c holds 4 u64s m_j, bit w = adj[r][c*256+w*4+j].
// Lane (m16,quad) at step kk (group g=kk>>3, j=kk&7) needs cols kk*32+quad*8..+7:
//   word = lo half of m_* for j<4 else hi half; s = (j&3)*8 + quad*2;
//   t_i = bfe(m_i_word, s, 2); cols 0..7 = t0&1,t1&1,t2&1,t3&1,t0&2,t1&2,t2&2,t3&2.
// Per group a strip's A-bits are 32 B (2 x i32x4), prefetched a group ahead in
// named regs (static indexing). No LDS, no barriers. B frags register-double-
// buffered from L2. Wave = 32 rows (2 strips): 9 B-loads feed 18 MFMAs per kk.
// Grid 512 = 64 mb x 8 ks; 4 waves/block.
__global__ __launch_bounds__(256, 2) void k_main(const unsigned long long* __restrict__ bm64,
                                                 const uint4* __restrict__ fragB,
                                                 float* __restrict__ accum) {
  const int mb = blockIdx.x >> 3;         // 0..63
  const int ks = blockIdx.x & 7;          // 0..7
  const int tid = threadIdx.x;
  const int wave = tid >> 6, lane = tid & 63;
  const int m16 = lane & 15, quad = lane >> 4;
  const int q2 = quad * 2;

  const int row0 = mb*128 + wave*32 + m16;              // strip0 row
  const i32x4* a0p = (const i32x4*)((const char*)bm64 + (size_t)row0*1024 + ks*128);
  const i32x4* a1p = a0p + 1024;                        // strip1 (+16 rows x 1 KB)
  const uu32x4* bb = (const uu32x4*)fragB + (size_t)(ks*32)*NTILES*64 + lane;

  f32x4 acc0[NTILES], acc1[NTILES];
#pragma unroll
  for (int n = 0; n < NTILES; n++) {
    acc0[n] = (f32x4){0.f, 0.f, 0.f, 0.f};
    acc1[n] = (f32x4){0.f, 0.f, 0.f, 0.f};
  }

  uu32x4 bvA[NTILES], bvB[NTILES];

  // unpack: given the 4 mask words for this j (already half-selected) and s,
  // build the bf16x8 A-fragment.
  auto unpack = [&](unsigned w0, unsigned w1, unsigned w2, unsigned w3,
                    int s) -> bf16x8 {
    const unsigned t0 = (w0 >> s) & 3u;
    const unsigned t1 = (w1 >> s) & 3u;
    const unsigned t2 = (w2 >> s) & 3u;
    const unsigned t3 = (w3 >> s) & 3u;
    unsigned u0 = (t0 & 1u ? 0x3F80u : 0u) | (t1 & 1u ? 0x3F800000u : 0u);
    unsigned u1 = (t2 & 1u ? 0x3F80u : 0u) | (t3 & 1u ? 0x3F800000u : 0u);
    unsigned u2 = (t0 & 2u ? 0x3F80u : 0u) | (t1 & 2u ? 0x3F800000u : 0u);
    unsigned u3 = (t2 & 2u ? 0x3F80u : 0u) | (t3 & 2u ? 0x3F800000u : 0u);
    uu32x4 u = {u0, u1, u2, u3};
    return __builtin_bit_cast(bf16x8, u);
  };

  // prologue: A group 0 (2 x i32x4 per strip), B(0)
  i32x4 c0a = a0p[0], c0b = a0p[1];       // strip0: {m0lo,m0hi,m1lo,m1hi},{m2lo,m2hi,m3lo,m3hi}
  i32x4 c1a = a1p[0], c1b = a1p[1];       // strip1
#pragma unroll
  for (int t = 0; t < NTILES; t++) bvA[t] = bb[(size_t)t*64];

  for (int g = 0; g < 4; ++g) {           // 4 groups x 8 kk-steps
    // prefetch next A group (g=3 overruns 32 B into ws padding — never used)
    i32x4 n0a = a0p[(g + 1)*2],     n0b = a0p[(g + 1)*2 + 1];
    i32x4 n1a = a1p[(g + 1)*2],     n1b = a1p[(g + 1)*2 + 1];
#pragma unroll
    for (int j = 0; j < 8; ++j) {
      const int kk = g*8 + j;
      // load B(kk+1) into the buffer not in use (kk=31 overruns 9 KB into ws — safe)
      const uu32x4* bp = bb + (size_t)(kk + 1)*NTILES*64;
      if ((j & 1) == 0) {
#pragma unroll
        for (int t = 0; t < NTILES; t++) bvB[t] = bp[(size_t)t*64];
      } else {
#pragma unroll
        for (int t = 0; t < NTILES; t++) bvA[t] = bp[(size_t)t*64];
      }
      // select halves statically (j literal after unroll)
      const int s = (j & 3)*8 + q2;
      bf16x8 af0, af1;
      if (j < 4) {
        af0 = unpack((unsigned)c0a[0], (unsigned)c0a[2],
                     (unsigned)c0b[0], (unsigned)c0b[2], s);
        af1 = unpack((unsigned)c1a[0], (unsigned)c1a[2],
                     (unsigned)c1b[0], (unsigned)c1b[2], s);
      } else {
        af0 = unpack((unsigned)c0a[1], (unsigned)c0a[3],
                     (unsigned)c0b[1], (unsigned)c0b[3], s);
        af1 = unpack((unsigned)c1a[1], (unsigned)c1a[3],
                     (unsigned)c1b[1], (unsigned)c1b[3], s);
      }
      const uu32x4* bv = ((j & 1) == 0) ? bvA : bvB;   // static after unroll
#pragma unroll
      for (int n = 0; n < NTILES; n++) {
        bf16x8 bfr = __builtin_bit_cast(bf16x8, bv[n]);
        acc0[n] = __builtin_amdgcn_mfma_f32_16x16x32_bf16(af0, bfr, acc0[n], 0, 0, 0);
      }
#pragma unroll
      for (int n = 0; n < NTILES; n++) {
        bf16x8 bfr = __builtin_bit_cast(bf16x8, bv[n]);
        acc1[n] = __builtin_amdgcn_mfma_f32_16x16x32_bf16(af1, bfr, acc1[n], 0, 0, 0);
      }
    }
    c0a = n0a; c0b = n0b; c1a = n1a; c1b = n1b;
  }

  // epilogue: C/D layout col=lane&15, row=quad*4+reg. Plain stores.
  const int rb0 = mb*128 + wave*32 + quad*4;
  float* op = accum + (size_t)ks*N_NODES*ACC_STRIDE;
#pragma unroll
  for (int n = 0; n < NTILES; n++) {
    if (n == 8 && m16 >= HEADS) continue;  // cols 130..143 are padding
#pragma unroll
    for (int r = 0; r < 4; r++) {
      op[(size_t)(rb0 + r)*ACC_STRIDE + n*16 + m16]      = acc0[n][r];
      op[(size_t)(rb0 + 16 + r)*ACC_STRIDE + n*16 + m16] = acc1[n][r];
    }
  }
}

// ---------------------------------------------------------------- k_div
// out[i][c] = (sum_ks num) / (sum_ks den); vectorized f32x4, 8 rows/block.
__global__ void k_div(const float* __restrict__ acc, float* __restrict__ out) {
  const int tid = threadIdx.x;
  const int r = tid >> 5, c4 = (tid & 31) << 2;   // 8 rows x 32 lanes x float4
  const int i = blockIdx.x * 8 + r;
  const int h = c4 >> 6;
  f32x4 num = (f32x4){0.f, 0.f, 0.f, 0.f};
  float den = 0.f;
#pragma unroll
  for (int s = 0; s < KSPLIT; s++) {
    const float* p = acc + ((size_t)s*N_NODES + i)*ACC_STRIDE;
    num += *(const f32x4*)(p + c4);
    den += p[FEAT + h];
  }
  f32x4 o = num / (f32x4){den, den, den, den};
  *(f32x4*)(out + (size_t)i*FEAT + c4) = o;
}

// ---------------------------------------------------------------- launch
extern "C" void kernel_launch(void* const* d_in, const int* in_sizes, int n_in,
                              void* d_out, int out_size, void* d_ws, size_t ws_size,
                              hipStream_t stream) {
  const float* x      = (const float*)d_in[0];
  const int*   adj    = (const int*)  d_in[1];
  const float* W      = (const float*)d_in[2];
  // d_in[3] = attn_l: cancels in softmax over j — unused.
  const float* attn_r = (const float*)d_in[4];

  char* ws = (char*)d_ws;
  uint4*              frag = (uint4*)(ws + 0);                 // 2.36 MB
  unsigned long long* bm64 = (unsigned long long*)(ws + (4u << 20));  // 8 MB @ 4 MB
  float*              acc  = (float*)(ws + (16u << 20));       // 8 x 4.33 MB @ 16 MB
  float*              out  = (float*)d_out;

  hipLaunchKernelGGL(k_pack, dim3(2048), dim3(256), 0, stream, adj, bm64);
  hipLaunchKernelGGL(k_prep, dim3(256),  dim3(256), 0, stream, x, W, attn_r, frag);
  hipLaunchKernelGGL(k_main, dim3(512),  dim3(256), 0, stream, bm64, frag, acc);
  hipLaunchKernelGGL(k_div,  dim3(1024), dim3(256), 0, stream, acc, out);
}

// Round 8
// 409.799 us; speedup vs baseline: 1.1922x; 1.0087x over previous
//
#include <hip/hip_runtime.h>
#include <cstdint>
#include <cstddef>

#define N_NODES 8192
#define IN_DIM  256
#define OUT_DIM 64
#define HEADS   2
#define FEAT    128           // OUT_DIM*HEADS
#define NTILES  9             // 144 B-cols: 128 feat + 2 denom + 14 pad
#define ACC_STRIDE 132
#define KSPLIT  8

typedef __bf16 bf16x8 __attribute__((ext_vector_type(8)));
typedef float  f32x4  __attribute__((ext_vector_type(4)));
typedef int    i32x4  __attribute__((ext_vector_type(4)));
typedef unsigned uu32x4 __attribute__((ext_vector_type(4)));

static __device__ __forceinline__ unsigned short f2bf(float f) {
  unsigned u = __float_as_uint(f);
  u += 0x7FFFu + ((u >> 16) & 1u);     // round-to-nearest-even
  return (unsigned short)(u >> 16);
}

// ---------------------------------------------------------------- k_pack
// Streaming bit-pack: 268 MB adj -> 8 MB bitmask. Wave reads 1 KB contiguous
// per instruction; ballot transpose; chunk c (cols c*256..+255) -> 4 u64 m_j,
// bit w of m_j = adj[row][c*256 + w*4 + j]. Layout bm64[row*128 + c*4 + j].
__global__ __launch_bounds__(256) void k_pack(const int* __restrict__ adj,
                                              unsigned long long* __restrict__ bm64) {
  const int tid = threadIdx.x;
  const int wv = tid >> 6, lane = tid & 63;
  const int row = blockIdx.x * 4 + wv;
  const i32x4* rp = (const i32x4*)(adj + (size_t)row * N_NODES) + lane;
  unsigned long long* op = bm64 + (size_t)row * 128;

  for (int c = 0; c < 32; c += 8) {
    i32x4 v[8];
#pragma unroll
    for (int i = 0; i < 8; ++i)
      v[i] = __builtin_nontemporal_load(rp + (size_t)(c + i) * 64);
#pragma unroll
    for (int i = 0; i < 8; ++i) {
      unsigned long long m0 = __ballot(v[i][0] != 0);
      unsigned long long m1 = __ballot(v[i][1] != 0);
      unsigned long long m2 = __ballot(v[i][2] != 0);
      unsigned long long m3 = __ballot(v[i][3] != 0);
      unsigned long long mv = (lane == 0) ? m0 : (lane == 1) ? m1
                            : (lane == 2) ? m2 : m3;
      if (lane < 4) op[(c + i) * 4 + lane] = mv;
    }
  }
}

// ---------------------------------------------------------------- k_prep
// Fused: H-tile matmul (registers) + er reduction + exp + bf16 fragment pack.
__global__ __launch_bounds__(256) void k_prep(const float* __restrict__ x,
                                              const float* __restrict__ W,
                                              const float* __restrict__ attn_r,
                                              uint4* __restrict__ frag) {
  const int kb = blockIdx.x;                 // 0..255
  const int tid = threadIdx.x;
  const int tx = tid & 15, ty = tid >> 4;    // ty 0..15
  const int j0 = kb * 32;

  __shared__ float xs[32][68];               // [row][k] 8.7 KB
  __shared__ float wl[128][68];              // [col][k] 34.8 KB
  __shared__ unsigned short pk[32][146];     // bf16 pack buffer 9.3 KB

  float acc[2][8] = {};                      // rows ty, ty+16; cols tx+jj*16

  for (int kc = 0; kc < IN_DIM; kc += 64) {
    __syncthreads();
#pragma unroll
    for (int p = 0; p < 2; p++) {
      const int slot = p*256 + tid;
      const int r = slot >> 4, k4 = slot & 15;
      *(float4*)&xs[r][k4*4] = *(const float4*)(x + (size_t)(j0 + r)*IN_DIM + kc + k4*4);
    }
#pragma unroll
    for (int p = 0; p < 8; p++) {
      const int slot = p*256 + tid;
      const int r = slot >> 4, k4 = slot & 15;
      *(float4*)&wl[r][k4*4] = *(const float4*)(W + (size_t)r*IN_DIM + kc + k4*4);
    }
    __syncthreads();
#pragma unroll
    for (int k4 = 0; k4 < 16; k4++) {
      float4 xr[2], wr[8];
#pragma unroll
      for (int i = 0; i < 2; i++) xr[i] = *(const float4*)&xs[ty + i*16][k4*4];
#pragma unroll
      for (int jj = 0; jj < 8; jj++) wr[jj] = *(const float4*)&wl[tx + jj*16][k4*4];
#pragma unroll
      for (int i = 0; i < 2; i++)
#pragma unroll
        for (int jj = 0; jj < 8; jj++)
          acc[i][jj] += xr[i].x*wr[jj].x + xr[i].y*wr[jj].y +
                        xr[i].z*wr[jj].z + xr[i].w*wr[jj].w;
    }
  }

  float ar[8];
#pragma unroll
  for (int jj = 0; jj < 8; jj++)
    ar[jj] = attn_r[((jj >> 2)) * OUT_DIM + ((tx + jj*16) & 63)];
  float e0[2] = {}, e1[2] = {};
#pragma unroll
  for (int i = 0; i < 2; i++) {
#pragma unroll
    for (int jj = 0; jj < 4; jj++) e0[i] += acc[i][jj] * ar[jj];
#pragma unroll
    for (int jj = 4; jj < 8; jj++) e1[i] += acc[i][jj] * ar[jj];
  }
#pragma unroll
  for (int m = 1; m <= 8; m <<= 1) {
#pragma unroll
    for (int i = 0; i < 2; i++) {
      e0[i] += __shfl_xor(e0[i], m);
      e1[i] += __shfl_xor(e1[i], m);
    }
  }
  float w0[2], w1[2];
#pragma unroll
  for (int i = 0; i < 2; i++) { w0[i] = __expf(e0[i]); w1[i] = __expf(e1[i]); }

#pragma unroll
  for (int i = 0; i < 2; i++) {
    const int row = ty + i*16;
#pragma unroll
    for (int jj = 0; jj < 8; jj++)
      pk[row][tx + jj*16] = f2bf((jj < 4 ? w0[i] : w1[i]) * acc[i][jj]);
    pk[row][128 + tx] = (tx == 0) ? f2bf(w0[i]) : (tx == 1) ? f2bf(w1[i]) : 0;
  }
  __syncthreads();

#pragma unroll
  for (int t = 0; t < 3; t++) {
    const int wid = t*256 + tid;
    if (wid < 576) {
      const int l = wid & 63, n = wid >> 6;
      const int col = n*16 + (l & 15), jb = (l >> 4) * 8;
      uint4 o;
      o.x = (unsigned)pk[jb+0][col] | ((unsigned)pk[jb+1][col] << 16);
      o.y = (unsigned)pk[jb+2][col] | ((unsigned)pk[jb+3][col] << 16);
      o.z = (unsigned)pk[jb+4][col] | ((unsigned)pk[jb+5][col] << 16);
      o.w = (unsigned)pk[jb+6][col] | ((unsigned)pk[jb+7][col] << 16);
      frag[((size_t)kb*NTILES + n)*64 + l] = o;
    }
  }
}

// ---------------------------------------------------------------- k_main
// accum[ks][8192][132] = adj[:, ks-slice] @ B[ks-slice, 144]  (bf16 MFMA, fp32 acc)
// 4-strip waves: 2 waves/block x 64 rows/wave (4 x 16-row MFMA strips) — one
// 9 KB B-load per wave per kk feeds 36 MFMAs (was 18), halving B L2 traffic;
// per-group s_barrier keeps the 2 waves lockstep so the second wave's B-loads
// hit L1. Bitmask A (ballot layout): per 8-kk group a strip's bits are 32 B
// (2 x i32x4), next group prefetched in named regs. B register-double-buffered.
// No LDS. ~330 VGPR at launch_bounds(128,1); grid 512 = 2 blocks/CU.
__global__ __launch_bounds__(128, 1) void k_main(const unsigned long long* __restrict__ bm64,
                                                 const uint4* __restrict__ fragB,
                                                 float* __restrict__ accum) {
  const int mb = blockIdx.x >> 3;         // 0..63
  const int ks = blockIdx.x & 7;          // 0..7
  const int tid = threadIdx.x;
  const int wave = tid >> 6, lane = tid & 63;
  const int m16 = lane & 15, quad = lane >> 4;
  const int q2 = quad * 2;

  const int row0 = mb*128 + wave*64 + m16;              // strip0 row
  const char* abase = (const char*)bm64 + (size_t)row0*1024 + ks*128;
  // strips s=0..3 at +s*16 rows = +s*16384 B
  const uu32x4* bb = (const uu32x4*)fragB + (size_t)(ks*32)*NTILES*64 + lane;

  f32x4 acc[4][NTILES];
#pragma unroll
  for (int s = 0; s < 4; s++)
#pragma unroll
    for (int n = 0; n < NTILES; n++) acc[s][n] = (f32x4){0.f, 0.f, 0.f, 0.f};

  uu32x4 bvA[NTILES], bvB[NTILES];
  i32x4 cA[4], cB[4];                     // current A group per strip
  i32x4 nA[4], nB[4];                     // next A group

  auto unpack = [&](unsigned w0, unsigned w1, unsigned w2, unsigned w3,
                    int s) -> bf16x8 {
    const unsigned t0 = (w0 >> s) & 3u;
    const unsigned t1 = (w1 >> s) & 3u;
    const unsigned t2 = (w2 >> s) & 3u;
    const unsigned t3 = (w3 >> s) & 3u;
    unsigned u0 = (t0 & 1u ? 0x3F80u : 0u) | (t1 & 1u ? 0x3F800000u : 0u);
    unsigned u1 = (t2 & 1u ? 0x3F80u : 0u) | (t3 & 1u ? 0x3F800000u : 0u);
    unsigned u2 = (t0 & 2u ? 0x3F80u : 0u) | (t1 & 2u ? 0x3F800000u : 0u);
    unsigned u3 = (t2 & 2u ? 0x3F80u : 0u) | (t3 & 2u ? 0x3F800000u : 0u);
    uu32x4 u = {u0, u1, u2, u3};
    return __builtin_bit_cast(bf16x8, u);
  };

  // prologue: A group 0 (all strips), B(0)
#pragma unroll
  for (int s = 0; s < 4; s++) {
    const i32x4* p = (const i32x4*)(abase + s*16384);
    cA[s] = p[0]; cB[s] = p[1];
  }
#pragma unroll
  for (int t = 0; t < NTILES; t++) bvA[t] = bb[(size_t)t*64];

  for (int g = 0; g < 4; ++g) {           // 4 groups x 8 kk-steps
    __builtin_amdgcn_s_barrier();         // loose 2-wave sync -> L1 B-reuse
    // prefetch next A group (g=3 over-reads 32 B into ws past bm64 — unused)
#pragma unroll
    for (int s = 0; s < 4; s++) {
      const i32x4* p = (const i32x4*)(abase + s*16384 + (g + 1)*32);
      nA[s] = p[0]; nB[s] = p[1];
    }
#pragma unroll
    for (int j = 0; j < 8; ++j) {
      const int kk = g*8 + j;
      // load B(kk+1) into the buffer not in use (kk=31 over-reads 9 KB into ws — safe)
      const uu32x4* bp = bb + (size_t)(kk + 1)*NTILES*64;
      if ((j & 1) == 0) {
#pragma unroll
        for (int t = 0; t < NTILES; t++) bvB[t] = bp[(size_t)t*64];
      } else {
#pragma unroll
        for (int t = 0; t < NTILES; t++) bvA[t] = bp[(size_t)t*64];
      }
      const int sh = (j & 3)*8 + q2;      // static after unroll
      bf16x8 af[4];
#pragma unroll
      for (int s = 0; s < 4; s++) {
        if (j < 4)
          af[s] = unpack((unsigned)cA[s][0], (unsigned)cA[s][2],
                         (unsigned)cB[s][0], (unsigned)cB[s][2], sh);
        else
          af[s] = unpack((unsigned)cA[s][1], (unsigned)cA[s][3],
                         (unsigned)cB[s][1], (unsigned)cB[s][3], sh);
      }
      const uu32x4* bv = ((j & 1) == 0) ? bvA : bvB;   // static after unroll
#pragma unroll
      for (int s = 0; s < 4; s++)
#pragma unroll
        for (int n = 0; n < NTILES; n++) {
          bf16x8 bfr = __builtin_bit_cast(bf16x8, bv[n]);
          acc[s][n] = __builtin_amdgcn_mfma_f32_16x16x32_bf16(af[s], bfr, acc[s][n], 0, 0, 0);
        }
    }
#pragma unroll
    for (int s = 0; s < 4; s++) { cA[s] = nA[s]; cB[s] = nB[s]; }
  }

  // epilogue: C/D layout col=lane&15, row=quad*4+reg. Plain stores.
  float* op = accum + (size_t)ks*N_NODES*ACC_STRIDE;
#pragma unroll
  for (int s = 0; s < 4; s++) {
    const int rb = mb*128 + wave*64 + s*16 + quad*4;
#pragma unroll
    for (int n = 0; n < NTILES; n++) {
      if (n == 8 && m16 >= HEADS) continue;  // cols 130..143 are padding
#pragma unroll
      for (int r = 0; r < 4; r++)
        op[(size_t)(rb + r)*ACC_STRIDE + n*16 + m16] = acc[s][n][r];
    }
  }
}

// ---------------------------------------------------------------- k_div
// out[i][c] = (sum_ks num) / (sum_ks den); vectorized f32x4, 8 rows/block.
__global__ void k_div(const float* __restrict__ acc, float* __restrict__ out) {
  const int tid = threadIdx.x;
  const int r = tid >> 5, c4 = (tid & 31) << 2;   // 8 rows x 32 lanes x float4
  const int i = blockIdx.x * 8 + r;
  const int h = c4 >> 6;
  f32x4 num = (f32x4){0.f, 0.f, 0.f, 0.f};
  float den = 0.f;
#pragma unroll
  for (int s = 0; s < KSPLIT; s++) {
    const float* p = acc + ((size_t)s*N_NODES + i)*ACC_STRIDE;
    num += *(const f32x4*)(p + c4);
    den += p[FEAT + h];
  }
  f32x4 o = num / (f32x4){den, den, den, den};
  *(f32x4*)(out + (size_t)i*FEAT + c4) = o;
}

// ---------------------------------------------------------------- launch
extern "C" void kernel_launch(void* const* d_in, const int* in_sizes, int n_in,
                              void* d_out, int out_size, void* d_ws, size_t ws_size,
                              hipStream_t stream) {
  const float* x      = (const float*)d_in[0];
  const int*   adj    = (const int*)  d_in[1];
  const float* W      = (const float*)d_in[2];
  // d_in[3] = attn_l: cancels in softmax over j — unused.
  const float* attn_r = (const float*)d_in[4];

  char* ws = (char*)d_ws;
  uint4*              frag = (uint4*)(ws + 0);                 // 2.36 MB
  unsigned long long* bm64 = (unsigned long long*)(ws + (4u << 20));  // 8 MB @ 4 MB
  float*              acc  = (float*)(ws + (16u << 20));       // 8 x 4.33 MB @ 16 MB
  float*              out  = (float*)d_out;

  hipLaunchKernelGGL(k_pack, dim3(2048), dim3(256), 0, stream, adj, bm64);
  hipLaunchKernelGGL(k_prep, dim3(256),  dim3(256), 0, stream, x, W, attn_r, frag);
  hipLaunchKernelGGL(k_main, dim3(512),  dim3(128), 0, stream, bm64, frag, acc);
  hipLaunchKernelGGL(k_div,  dim3(1024), dim3(256), 0, stream, acc, out);
}